// Round 10
// baseline (451.719 us; speedup 1.0000x reference)
//
#include <hip/hip_runtime.h>
#include <math.h>

#define T_TOK 4096
#define H_DIM 1024
#define I_DIM 2048
#define E_NUM 8
#define CAP   2048
#define BM 128
#define BN 128
#define BK 64

typedef __attribute__((ext_vector_type(8))) short bf16x8;
typedef __attribute__((ext_vector_type(4))) float f32x4;

__device__ __forceinline__ unsigned short f2bf(float f) {
    union { float f; unsigned int u; } v; v.f = f;
    unsigned int r = v.u + 0x7FFFu + ((v.u >> 16) & 1u);
    return (unsigned short)(r >> 16);
}

__device__ __forceinline__ void gl_lds16(const void* g, void* l) {
    __builtin_amdgcn_global_load_lds(
        (const __attribute__((address_space(1))) void*)g,
        (__attribute__((address_space(3))) void*)l, 16, 0, 0);
}

// ---------------- Router + list build (fused) --------------------------------
__global__ __launch_bounds__(256) void moe_router(
    const float* __restrict__ x, const float* __restrict__ gate,
    int* __restrict__ counts, int* __restrict__ list_tok, float* __restrict__ list_w)
{
    const int wave = threadIdx.x >> 6;
    const int lane = threadIdx.x & 63;
    const int t = blockIdx.x * 4 + wave;

    float acc[E_NUM];
#pragma unroll
    for (int e = 0; e < E_NUM; ++e) acc[e] = 0.f;
    const float* xp = x + (size_t)t * H_DIM;
    for (int k = lane; k < H_DIM; k += 64) {
        const float xv = xp[k];
#pragma unroll
        for (int e = 0; e < E_NUM; ++e) acc[e] += xv * gate[e * H_DIM + k];
    }
#pragma unroll
    for (int e = 0; e < E_NUM; ++e) {
#pragma unroll
        for (int off = 32; off > 0; off >>= 1)
            acc[e] += __shfl_xor(acc[e], off, 64);
    }
    if (lane == 0) {
        float m = acc[0];
#pragma unroll
        for (int e = 1; e < E_NUM; ++e) m = fmaxf(m, acc[e]);
        float p[E_NUM]; float Z = 0.f;
#pragma unroll
        for (int e = 0; e < E_NUM; ++e) { p[e] = expf(acc[e] - m); Z += p[e]; }
        const float invZ = 1.f / Z;
        int i1 = 0, i2 = 0; float v1 = -1.f, v2 = -1.f;
#pragma unroll
        for (int e = 0; e < E_NUM; ++e) {
            const float pe = p[e] * invZ;
            if (pe > v1)      { v2 = v1; i2 = i1; v1 = pe; i1 = e; }
            else if (pe > v2) { v2 = pe; i2 = e; }
        }
        const float s = 1.f / (v1 + v2 + 1e-9f);
        int p1 = atomicAdd(&counts[i1], 1);
        if (p1 < CAP) { list_tok[i1 * CAP + p1] = t; list_w[i1 * CAP + p1] = v1 * s; }
        int p2 = atomicAdd(&counts[i2], 1);
        if (p2 < CAP) { list_tok[i2 * CAP + p2] = t; list_w[i2 * CAP + p2] = v2 * s; }
    }
}

// ---------------- Gather X rows -> bf16 Xg[e][CAP][H] -----------------------
__global__ __launch_bounds__(256) void moe_gather(
    const float* __restrict__ x, const int* __restrict__ counts,
    const int* __restrict__ list_tok, unsigned short* __restrict__ Xg)
{
    const int e = blockIdx.y;
    const int r = blockIdx.x;
    if (r >= min(counts[e], CAP)) return;
    const int tok = list_tok[e * CAP + r];
    const float4 v = ((const float4*)(x + (size_t)tok * H_DIM))[threadIdx.x];
    ushort4 o = make_ushort4(f2bf(v.x), f2bf(v.y), f2bf(v.z), f2bf(v.w));
    *(ushort4*)(Xg + (size_t)(e * CAP + r) * H_DIM + threadIdx.x * 4) = o;
}

// ---------------- Transpose-convert: [E][R][C] f32 -> [E][C][R] bf16 --------
__global__ __launch_bounds__(256) void transpose_bf16(
    const float* __restrict__ in, unsigned short* __restrict__ outp, int R, int C)
{
    __shared__ unsigned short t[64][72];
    const int e = blockIdx.z;
    const float* src = in + (size_t)e * R * C;
    unsigned short* dst = outp + (size_t)e * R * C;
    const int c0 = blockIdx.x * 64;
    const int r0 = blockIdx.y * 64;
    const int tx = (threadIdx.x & 15) << 2;
    const int ty = threadIdx.x >> 4;
#pragma unroll
    for (int s = 0; s < 4; ++s) {
        const int r = ty + s * 16;
        const float4 v = *(const float4*)&src[(size_t)(r0 + r) * C + c0 + tx];
        t[tx + 0][r] = f2bf(v.x);
        t[tx + 1][r] = f2bf(v.y);
        t[tx + 2][r] = f2bf(v.z);
        t[tx + 3][r] = f2bf(v.w);
    }
    __syncthreads();
    const int cc = threadIdx.x >> 3;
    const int rr = (threadIdx.x & 7) << 3;
#pragma unroll
    for (int s = 0; s < 2; ++s) {
        const int c = cc + s * 32;
        *(bf16x8*)&dst[(size_t)(c0 + c) * R + r0 + rr] = *(const bf16x8*)&t[c][rr];
    }
}

// ---- LDS swizzle (T2, rule #21): linear gl_lds dest + inverse-swizzled
// global source + swizzled read. LDS[row][slot] holds global k-slot
// slot^(row&7); row&7 == lane>>3 at stage, == lane&7 at read.

// ---------------- GEMM1: hmid = silu(Xg @ Wup), dbuf + swizzle --------------
__global__ __launch_bounds__(256) void moe_gemm1(
    const unsigned short* __restrict__ Xg, const unsigned short* __restrict__ WupT,
    const int* __restrict__ counts, unsigned short* __restrict__ hmid)
{
    __shared__ unsigned short As[2][BM][BK];
    __shared__ unsigned short Bs[2][BN][BK];
    const int s_id = blockIdx.x;
    const int l = (s_id & 7) * 256 + (s_id >> 3);  // bijective: 2048 = 8*256
    const int e = l >> 8;
    const int bx = l & 15;
    const int by = (l >> 4) & 15;
    const int cnt = min(counts[e], CAP);
    const int row0 = bx * BM;
    if (row0 >= cnt) return;
    const int n0 = by * BN;
    const int tid = threadIdx.x;
    const int lane = tid & 63;
    const int wid = tid >> 6;
    const int wm = wid >> 1, wn = wid & 1;

    const unsigned short* Ae = Xg + (size_t)e * CAP * H_DIM;
    const unsigned short* Be = WupT + (size_t)e * (size_t)I_DIM * H_DIM;

    const int sub = lane >> 3;                       // row within 8-row chunk
    const int kus = ((lane & 7) ^ sub) * 8;          // inverse-swizzled k source

#define STAGE1(buf, kt)                                                       \
    {                                                                         \
        _Pragma("unroll")                                                     \
        for (int c = 0; c < 4; ++c) {                                         \
            const int row = (c * 4 + wid) * 8 + sub;                          \
            gl_lds16(Ae + (size_t)(row0 + row) * H_DIM + (kt) + kus,          \
                     (char*)&As[buf][0][0] + (c * 4 + wid) * 1024);           \
            gl_lds16(Be + (size_t)(n0 + row) * H_DIM + (kt) + kus,            \
                     (char*)&Bs[buf][0][0] + (c * 4 + wid) * 1024);           \
        }                                                                     \
    }

    f32x4 acc[4][4];
#pragma unroll
    for (int m = 0; m < 4; ++m)
#pragma unroll
        for (int n = 0; n < 4; ++n) acc[m][n] = (f32x4){0.f, 0.f, 0.f, 0.f};

    STAGE1(0, 0);
    __syncthreads();
    int cur = 0;
    for (int kt = 0; kt < H_DIM; kt += BK) {
        if (kt + BK < H_DIM) STAGE1(cur ^ 1, kt + BK);
#pragma unroll
        for (int kk = 0; kk < BK; kk += 32) {
            // swizzled k-slot: ((kk>>3)|(lane>>4)) ^ (lane&7), row&7 == lane&7
            const int koff = ((((kk >> 3) | (lane >> 4)) ^ (lane & 7)) << 3);
            bf16x8 a[4], b[4];
#pragma unroll
            for (int m = 0; m < 4; ++m)
                a[m] = *(const bf16x8*)&As[cur][wm * 64 + m * 16 + (lane & 15)][koff];
#pragma unroll
            for (int n = 0; n < 4; ++n)
                b[n] = *(const bf16x8*)&Bs[cur][wn * 64 + n * 16 + (lane & 15)][koff];
#pragma unroll
            for (int m = 0; m < 4; ++m)
#pragma unroll
                for (int n = 0; n < 4; ++n)
                    acc[m][n] = __builtin_amdgcn_mfma_f32_16x16x32_bf16(
                        a[m], b[n], acc[m][n], 0, 0, 0);
        }
        __syncthreads();
        cur ^= 1;
    }
#undef STAGE1

    unsigned short* He = hmid + (size_t)e * CAP * I_DIM;
#pragma unroll
    for (int m = 0; m < 4; ++m) {
        const int rb = row0 + wm * 64 + m * 16 + ((lane >> 4) << 2);
#pragma unroll
        for (int n = 0; n < 4; ++n) {
            const int col = n0 + wn * 64 + n * 16 + (lane & 15);
#pragma unroll
            for (int j = 0; j < 4; ++j) {
                const float v = acc[m][n][j];
                const float s = v / (1.f + __expf(-v));
                He[(size_t)(rb + j) * I_DIM + col] = f2bf(s);
            }
        }
    }
}

// ---------------- GEMM2: out += w * (hmid @ Wdown), K-split x2, dbuf+swz ----
__global__ __launch_bounds__(256) void moe_gemm2(
    const unsigned short* __restrict__ hmid, const unsigned short* __restrict__ WdownT,
    const int* __restrict__ counts, const int* __restrict__ list_tok,
    const float* __restrict__ list_w, float* __restrict__ out)
{
    __shared__ unsigned short As[2][BM][BK];
    __shared__ unsigned short Bs[2][BN][BK];
    const int s_id = blockIdx.x;
    const int l = (s_id & 7) * 256 + (s_id >> 3);  // bijective: 2048 = 8*256
    const int e = l >> 8;
    const int bx = l & 15;
    const int by = (l >> 4) & 7;
    const int kh = (l >> 7) & 1;
    const int cnt = min(counts[e], CAP);
    const int row0 = bx * BM;
    if (row0 >= cnt) return;
    const int n0 = by * BN;
    const int kbase = kh * (I_DIM / 2);
    const int tid = threadIdx.x;
    const int lane = tid & 63;
    const int wid = tid >> 6;
    const int wm = wid >> 1, wn = wid & 1;

    const unsigned short* Ae = hmid + (size_t)e * CAP * I_DIM;
    const unsigned short* Be = WdownT + (size_t)e * (size_t)H_DIM * I_DIM;

    const int sub = lane >> 3;
    const int kus = ((lane & 7) ^ sub) * 8;          // inverse-swizzled k source

#define STAGE2(buf, kt)                                                       \
    {                                                                         \
        _Pragma("unroll")                                                     \
        for (int c = 0; c < 4; ++c) {                                         \
            const int row = (c * 4 + wid) * 8 + sub;                          \
            gl_lds16(Ae + (size_t)(row0 + row) * I_DIM + kbase + (kt) + kus,  \
                     (char*)&As[buf][0][0] + (c * 4 + wid) * 1024);           \
            gl_lds16(Be + (size_t)(n0 + row) * I_DIM + kbase + (kt) + kus,    \
                     (char*)&Bs[buf][0][0] + (c * 4 + wid) * 1024);           \
        }                                                                     \
    }

    f32x4 acc[4][4];
#pragma unroll
    for (int m = 0; m < 4; ++m)
#pragma unroll
        for (int n = 0; n < 4; ++n) acc[m][n] = (f32x4){0.f, 0.f, 0.f, 0.f};

    STAGE2(0, 0);
    __syncthreads();
    int cur = 0;
    for (int kt = 0; kt < I_DIM / 2; kt += BK) {
        if (kt + BK < I_DIM / 2) STAGE2(cur ^ 1, kt + BK);
#pragma unroll
        for (int kk = 0; kk < BK; kk += 32) {
            const int koff = ((((kk >> 3) | (lane >> 4)) ^ (lane & 7)) << 3);
            bf16x8 a[4], b[4];
#pragma unroll
            for (int m = 0; m < 4; ++m)
                a[m] = *(const bf16x8*)&As[cur][wm * 64 + m * 16 + (lane & 15)][koff];
#pragma unroll
            for (int n = 0; n < 4; ++n)
                b[n] = *(const bf16x8*)&Bs[cur][wn * 64 + n * 16 + (lane & 15)][koff];
#pragma unroll
            for (int m = 0; m < 4; ++m)
#pragma unroll
                for (int n = 0; n < 4; ++n)
                    acc[m][n] = __builtin_amdgcn_mfma_f32_16x16x32_bf16(
                        a[m], b[n], acc[m][n], 0, 0, 0);
        }
        __syncthreads();
        cur ^= 1;
    }
#undef STAGE2

#pragma unroll
    for (int m = 0; m < 4; ++m) {
#pragma unroll
        for (int j = 0; j < 4; ++j) {
            const int gr = row0 + wm * 64 + m * 16 + ((lane >> 4) << 2) + j;
            if (gr < cnt) {
                const int tok = list_tok[e * CAP + gr];
                const float w = list_w[e * CAP + gr];
                float* op = out + (size_t)tok * H_DIM + n0 + wn * 64 + (lane & 15);
#pragma unroll
                for (int n = 0; n < 4; ++n)
                    atomicAdd(op + n * 16, w * acc[m][n][j]);
            }
        }
    }
}

extern "C" void kernel_launch(void* const* d_in, const int* in_sizes, int n_in,
                              void* d_out, int out_size, void* d_ws, size_t ws_size,
                              hipStream_t stream)
{
    const float* x      = (const float*)d_in[0];   // [T, H]
    const float* gate   = (const float*)d_in[1];   // [E, H]
    const float* w_up   = (const float*)d_in[2];   // [E, H, I]
    const float* w_down = (const float*)d_in[3];   // [E, I, H]
    float* out = (float*)d_out;                    // [T, H]

    char* ws = (char*)d_ws;
    int*   counts   = (int*)(ws);                          // 1 KB
    int*   list_tok = (int*)(ws + 1024);                   // 64 KB
    float* list_w   = (float*)(ws + 66560);                // 64 KB
    unsigned short* Xg     = (unsigned short*)(ws + 132096);                  // 32 MB
    unsigned short* WupT   = (unsigned short*)(ws + 132096 + 33554432ull);    // 32 MB
    unsigned short* WdownT = (unsigned short*)(ws + 132096 + 67108864ull);    // 32 MB
    unsigned short* hmid   = (unsigned short*)(ws + 132096 + 100663296ull);   // 64 MB

    hipMemsetAsync(counts, 0, 1024, stream);
    hipMemsetAsync(out, 0, (size_t)out_size * sizeof(float), stream);

    moe_router<<<T_TOK / 4, 256, 0, stream>>>(x, gate, counts, list_tok, list_w);
    moe_gather<<<dim3(CAP, E_NUM), 256, 0, stream>>>(x, counts, list_tok, Xg);
    transpose_bf16<<<dim3(I_DIM / 64, H_DIM / 64, E_NUM), 256, 0, stream>>>(w_up, WupT, H_DIM, I_DIM);
    transpose_bf16<<<dim3(H_DIM / 64, I_DIM / 64, E_NUM), 256, 0, stream>>>(w_down, WdownT, I_DIM, H_DIM);
    moe_gemm1<<<2048, 256, 0, stream>>>(Xg, WupT, counts, hmid);
    moe_gemm2<<<2048, 256, 0, stream>>>(hmid, WdownT, counts, list_tok, list_w, out);
}

// Round 15
// 369.271 us; speedup vs baseline: 1.2233x; 1.2233x over previous
//
#include <hip/hip_runtime.h>
#include <math.h>

#define T_TOK 4096
#define H_DIM 1024
#define I_DIM 2048
#define E_NUM 8
#define CAP   2048
#define BM 128
#define BN 128
#define BK 64

typedef __attribute__((ext_vector_type(8))) short bf16x8;
typedef __attribute__((ext_vector_type(4))) float f32x4;

__device__ __forceinline__ unsigned short f2bf(float f) {
    union { float f; unsigned int u; } v; v.f = f;
    unsigned int r = v.u + 0x7FFFu + ((v.u >> 16) & 1u);
    return (unsigned short)(r >> 16);
}

__device__ __forceinline__ void gl_lds16(const void* g, void* l) {
    __builtin_amdgcn_global_load_lds(
        (const __attribute__((address_space(1))) void*)g,
        (__attribute__((address_space(3))) void*)l, 16, 0, 0);
}

// ---------------- Router (atomic-free): logits -> top2 -> weights -----------
__global__ __launch_bounds__(256) void moe_router(
    const float* __restrict__ x, const float* __restrict__ gate,
    int* __restrict__ topk_idx, float* __restrict__ topk_w)
{
    const int wave = threadIdx.x >> 6;
    const int lane = threadIdx.x & 63;
    const int t = blockIdx.x * 4 + wave;

    float acc[E_NUM];
#pragma unroll
    for (int e = 0; e < E_NUM; ++e) acc[e] = 0.f;
    const float* xp = x + (size_t)t * H_DIM;
    for (int k = lane; k < H_DIM; k += 64) {
        const float xv = xp[k];
#pragma unroll
        for (int e = 0; e < E_NUM; ++e) acc[e] += xv * gate[e * H_DIM + k];
    }
#pragma unroll
    for (int e = 0; e < E_NUM; ++e) {
#pragma unroll
        for (int off = 32; off > 0; off >>= 1)
            acc[e] += __shfl_xor(acc[e], off, 64);
    }
    if (lane == 0) {
        float m = acc[0];
#pragma unroll
        for (int e = 1; e < E_NUM; ++e) m = fmaxf(m, acc[e]);
        float p[E_NUM]; float Z = 0.f;
#pragma unroll
        for (int e = 0; e < E_NUM; ++e) { p[e] = expf(acc[e] - m); Z += p[e]; }
        const float invZ = 1.f / Z;
        int i1 = 0, i2 = 0; float v1 = -1.f, v2 = -1.f;
#pragma unroll
        for (int e = 0; e < E_NUM; ++e) {
            const float pe = p[e] * invZ;
            if (pe > v1)      { v2 = v1; i2 = i1; v1 = pe; i1 = e; }
            else if (pe > v2) { v2 = pe; i2 = e; }
        }
        const float s = 1.f / (v1 + v2 + 1e-9f);
        topk_idx[t * 2 + 0] = i1; topk_idx[t * 2 + 1] = i2;
        topk_w[t * 2 + 0] = v1 * s; topk_w[t * 2 + 1] = v2 * s;
    }
}

// ---------------- Build per-expert lists: ballot-prefix scan, NO atomics ----
// One block per expert; deterministic token order.
__global__ __launch_bounds__(256) void moe_build(
    const int* __restrict__ topk_idx, const float* __restrict__ topk_w,
    int* __restrict__ counts, int* __restrict__ list_tok, float* __restrict__ list_w)
{
    const int e = blockIdx.x;
    const int tid = threadIdx.x;
    const int wv = tid >> 6, lane = tid & 63;
    __shared__ int wsum[4];
    int base = 0;
    for (int c = 0; c < T_TOK; c += 256) {
        const int t = c + tid;
        const int i0 = topk_idx[t * 2 + 0];
        const int i1 = topk_idx[t * 2 + 1];
        const int match = (i0 == e) || (i1 == e);
        const float w = (i0 == e) ? topk_w[t * 2 + 0] : topk_w[t * 2 + 1];
        const unsigned long long mask = __ballot(match);
        const int my = __popcll(mask & ((1ull << lane) - 1ull));
        if (lane == 0) wsum[wv] = __popcll(mask);
        __syncthreads();
        int woff = 0;
#pragma unroll
        for (int i = 0; i < 4; ++i) if (i < wv) woff += wsum[i];
        const int ctot = wsum[0] + wsum[1] + wsum[2] + wsum[3];
        if (match) {
            const int pos = base + woff + my;
            if (pos < CAP) { list_tok[e * CAP + pos] = t; list_w[e * CAP + pos] = w; }
        }
        base += ctot;
        __syncthreads();
    }
    if (tid == 0) counts[e] = min(base, CAP);
}

// ---------------- Gather X rows -> bf16 Xg[e][CAP][H] -----------------------
__global__ __launch_bounds__(256) void moe_gather(
    const float* __restrict__ x, const int* __restrict__ counts,
    const int* __restrict__ list_tok, unsigned short* __restrict__ Xg)
{
    const int e = blockIdx.y;
    const int r = blockIdx.x;
    if (r >= min(counts[e], CAP)) return;
    const int tok = list_tok[e * CAP + r];
    const float4 v = ((const float4*)(x + (size_t)tok * H_DIM))[threadIdx.x];
    ushort4 o = make_ushort4(f2bf(v.x), f2bf(v.y), f2bf(v.z), f2bf(v.w));
    *(ushort4*)(Xg + (size_t)(e * CAP + r) * H_DIM + threadIdx.x * 4) = o;
}

// ---------------- Transpose-convert: [E][R][C] f32 -> [E][C][R] bf16 --------
__global__ __launch_bounds__(256) void transpose_bf16(
    const float* __restrict__ in, unsigned short* __restrict__ outp, int R, int C)
{
    __shared__ unsigned short t[64][72];
    const int e = blockIdx.z;
    const float* src = in + (size_t)e * R * C;
    unsigned short* dst = outp + (size_t)e * R * C;
    const int c0 = blockIdx.x * 64;
    const int r0 = blockIdx.y * 64;
    const int tx = (threadIdx.x & 15) << 2;
    const int ty = threadIdx.x >> 4;
#pragma unroll
    for (int s = 0; s < 4; ++s) {
        const int r = ty + s * 16;
        const float4 v = *(const float4*)&src[(size_t)(r0 + r) * C + c0 + tx];
        t[tx + 0][r] = f2bf(v.x);
        t[tx + 1][r] = f2bf(v.y);
        t[tx + 2][r] = f2bf(v.z);
        t[tx + 3][r] = f2bf(v.w);
    }
    __syncthreads();
    const int cc = threadIdx.x >> 3;
    const int rr = (threadIdx.x & 7) << 3;
#pragma unroll
    for (int s = 0; s < 2; ++s) {
        const int c = cc + s * 32;
        *(bf16x8*)&dst[(size_t)(c0 + c) * R + r0 + rr] = *(const bf16x8*)&t[c][rr];
    }
}

// ---- LDS swizzle (T2, rule #21): linear gl_lds dest + inverse-swizzled
// global source + swizzled read. LDS[row][slot] holds global k-slot
// slot^(row&7); row&7 == lane>>3 at stage, == lane&7 at read.

// ---------------- GEMM1: hmid = silu(Xg @ Wup), dbuf + swizzle --------------
__global__ __launch_bounds__(256) void moe_gemm1(
    const unsigned short* __restrict__ Xg, const unsigned short* __restrict__ WupT,
    const int* __restrict__ counts, unsigned short* __restrict__ hmid)
{
    __shared__ unsigned short As[2][BM][BK];
    __shared__ unsigned short Bs[2][BN][BK];
    const int s_id = blockIdx.x;
    const int l = (s_id & 7) * 256 + (s_id >> 3);  // bijective: 2048 = 8*256
    const int e = l >> 8;
    const int bx = l & 15;
    const int by = (l >> 4) & 15;
    const int cnt = min(counts[e], CAP);
    const int row0 = bx * BM;
    if (row0 >= cnt) return;
    const int n0 = by * BN;
    const int tid = threadIdx.x;
    const int lane = tid & 63;
    const int wid = tid >> 6;
    const int wm = wid >> 1, wn = wid & 1;

    const unsigned short* Ae = Xg + (size_t)e * CAP * H_DIM;
    const unsigned short* Be = WupT + (size_t)e * (size_t)I_DIM * H_DIM;

    const int sub = lane >> 3;                       // row within 8-row chunk
    const int kus = ((lane & 7) ^ sub) * 8;          // inverse-swizzled k source

#define STAGE1(buf, kt)                                                       \
    {                                                                         \
        _Pragma("unroll")                                                     \
        for (int c = 0; c < 4; ++c) {                                         \
            const int row = (c * 4 + wid) * 8 + sub;                          \
            gl_lds16(Ae + (size_t)(row0 + row) * H_DIM + (kt) + kus,          \
                     (char*)&As[buf][0][0] + (c * 4 + wid) * 1024);           \
            gl_lds16(Be + (size_t)(n0 + row) * H_DIM + (kt) + kus,            \
                     (char*)&Bs[buf][0][0] + (c * 4 + wid) * 1024);           \
        }                                                                     \
    }

    f32x4 acc[4][4];
#pragma unroll
    for (int m = 0; m < 4; ++m)
#pragma unroll
        for (int n = 0; n < 4; ++n) acc[m][n] = (f32x4){0.f, 0.f, 0.f, 0.f};

    STAGE1(0, 0);
    __syncthreads();
    int cur = 0;
    for (int kt = 0; kt < H_DIM; kt += BK) {
        if (kt + BK < H_DIM) STAGE1(cur ^ 1, kt + BK);
#pragma unroll
        for (int kk = 0; kk < BK; kk += 32) {
            const int koff = ((((kk >> 3) | (lane >> 4)) ^ (lane & 7)) << 3);
            bf16x8 a[4], b[4];
#pragma unroll
            for (int m = 0; m < 4; ++m)
                a[m] = *(const bf16x8*)&As[cur][wm * 64 + m * 16 + (lane & 15)][koff];
#pragma unroll
            for (int n = 0; n < 4; ++n)
                b[n] = *(const bf16x8*)&Bs[cur][wn * 64 + n * 16 + (lane & 15)][koff];
#pragma unroll
            for (int m = 0; m < 4; ++m)
#pragma unroll
                for (int n = 0; n < 4; ++n)
                    acc[m][n] = __builtin_amdgcn_mfma_f32_16x16x32_bf16(
                        a[m], b[n], acc[m][n], 0, 0, 0);
        }
        __syncthreads();
        cur ^= 1;
    }
#undef STAGE1

    unsigned short* He = hmid + (size_t)e * CAP * I_DIM;
#pragma unroll
    for (int m = 0; m < 4; ++m) {
        const int rb = row0 + wm * 64 + m * 16 + ((lane >> 4) << 2);
#pragma unroll
        for (int n = 0; n < 4; ++n) {
            const int col = n0 + wn * 64 + n * 16 + (lane & 15);
#pragma unroll
            for (int j = 0; j < 4; ++j) {
                const float v = acc[m][n][j];
                const float s = v / (1.f + __expf(-v));
                He[(size_t)(rb + j) * I_DIM + col] = f2bf(s);
            }
        }
    }
}

// ---------------- GEMM2: out += w * (hmid @ Wdown), K-split x2, dbuf+swz ----
__global__ __launch_bounds__(256) void moe_gemm2(
    const unsigned short* __restrict__ hmid, const unsigned short* __restrict__ WdownT,
    const int* __restrict__ counts, const int* __restrict__ list_tok,
    const float* __restrict__ list_w, float* __restrict__ out)
{
    __shared__ unsigned short As[2][BM][BK];
    __shared__ unsigned short Bs[2][BN][BK];
    const int s_id = blockIdx.x;
    const int l = (s_id & 7) * 256 + (s_id >> 3);  // bijective: 2048 = 8*256
    const int e = l >> 8;
    const int bx = l & 15;
    const int by = (l >> 4) & 7;
    const int kh = (l >> 7) & 1;
    const int cnt = min(counts[e], CAP);
    const int row0 = bx * BM;
    if (row0 >= cnt) return;
    const int n0 = by * BN;
    const int kbase = kh * (I_DIM / 2);
    const int tid = threadIdx.x;
    const int lane = tid & 63;
    const int wid = tid >> 6;
    const int wm = wid >> 1, wn = wid & 1;

    const unsigned short* Ae = hmid + (size_t)e * CAP * I_DIM;
    const unsigned short* Be = WdownT + (size_t)e * (size_t)H_DIM * I_DIM;

    const int sub = lane >> 3;
    const int kus = ((lane & 7) ^ sub) * 8;

#define STAGE2(buf, kt)                                                       \
    {                                                                         \
        _Pragma("unroll")                                                     \
        for (int c = 0; c < 4; ++c) {                                         \
            const int row = (c * 4 + wid) * 8 + sub;                          \
            gl_lds16(Ae + (size_t)(row0 + row) * I_DIM + kbase + (kt) + kus,  \
                     (char*)&As[buf][0][0] + (c * 4 + wid) * 1024);           \
            gl_lds16(Be + (size_t)(n0 + row) * I_DIM + kbase + (kt) + kus,    \
                     (char*)&Bs[buf][0][0] + (c * 4 + wid) * 1024);           \
        }                                                                     \
    }

    f32x4 acc[4][4];
#pragma unroll
    for (int m = 0; m < 4; ++m)
#pragma unroll
        for (int n = 0; n < 4; ++n) acc[m][n] = (f32x4){0.f, 0.f, 0.f, 0.f};

    STAGE2(0, 0);
    __syncthreads();
    int cur = 0;
    for (int kt = 0; kt < I_DIM / 2; kt += BK) {
        if (kt + BK < I_DIM / 2) STAGE2(cur ^ 1, kt + BK);
#pragma unroll
        for (int kk = 0; kk < BK; kk += 32) {
            const int koff = ((((kk >> 3) | (lane >> 4)) ^ (lane & 7)) << 3);
            bf16x8 a[4], b[4];
#pragma unroll
            for (int m = 0; m < 4; ++m)
                a[m] = *(const bf16x8*)&As[cur][wm * 64 + m * 16 + (lane & 15)][koff];
#pragma unroll
            for (int n = 0; n < 4; ++n)
                b[n] = *(const bf16x8*)&Bs[cur][wn * 64 + n * 16 + (lane & 15)][koff];
#pragma unroll
            for (int m = 0; m < 4; ++m)
#pragma unroll
                for (int n = 0; n < 4; ++n)
                    acc[m][n] = __builtin_amdgcn_mfma_f32_16x16x32_bf16(
                        a[m], b[n], acc[m][n], 0, 0, 0);
        }
        __syncthreads();
        cur ^= 1;
    }
#undef STAGE2

#pragma unroll
    for (int m = 0; m < 4; ++m) {
#pragma unroll
        for (int j = 0; j < 4; ++j) {
            const int gr = row0 + wm * 64 + m * 16 + ((lane >> 4) << 2) + j;
            if (gr < cnt) {
                const int tok = list_tok[e * CAP + gr];
                const float w = list_w[e * CAP + gr];
                float* op = out + (size_t)tok * H_DIM + n0 + wn * 64 + (lane & 15);
#pragma unroll
                for (int n = 0; n < 4; ++n)
                    atomicAdd(op + n * 16, w * acc[m][n][j]);
            }
        }
    }
}

extern "C" void kernel_launch(void* const* d_in, const int* in_sizes, int n_in,
                              void* d_out, int out_size, void* d_ws, size_t ws_size,
                              hipStream_t stream)
{
    const float* x      = (const float*)d_in[0];   // [T, H]
    const float* gate   = (const float*)d_in[1];   // [E, H]
    const float* w_up   = (const float*)d_in[2];   // [E, H, I]
    const float* w_down = (const float*)d_in[3];   // [E, I, H]
    float* out = (float*)d_out;                    // [T, H]

    char* ws = (char*)d_ws;
    int*   counts   = (int*)(ws);                          // 1 KB
    int*   topk_idx = (int*)(ws + 1024);                   // 32 KB
    float* topk_w   = (float*)(ws + 33792);                // 32 KB
    int*   list_tok = (int*)(ws + 66560);                  // 64 KB
    float* list_w   = (float*)(ws + 132096);               // 64 KB
    unsigned short* Xg     = (unsigned short*)(ws + 197632);                  // 32 MB
    unsigned short* WupT   = (unsigned short*)(ws + 197632 + 33554432ull);    // 32 MB
    unsigned short* WdownT = (unsigned short*)(ws + 197632 + 67108864ull);    // 32 MB
    unsigned short* hmid   = (unsigned short*)(ws + 197632 + 100663296ull);   // 64 MB

    hipMemsetAsync(out, 0, (size_t)out_size * sizeof(float), stream);

    moe_router<<<T_TOK / 4, 256, 0, stream>>>(x, gate, topk_idx, topk_w);
    moe_build<<<E_NUM, 256, 0, stream>>>(topk_idx, topk_w, counts, list_tok, list_w);
    moe_gather<<<dim3(CAP, E_NUM), 256, 0, stream>>>(x, counts, list_tok, Xg);
    transpose_bf16<<<dim3(I_DIM / 64, H_DIM / 64, E_NUM), 256, 0, stream>>>(w_up, WupT, H_DIM, I_DIM);
    transpose_bf16<<<dim3(H_DIM / 64, I_DIM / 64, E_NUM), 256, 0, stream>>>(w_down, WdownT, I_DIM, H_DIM);
    moe_gemm1<<<2048, 256, 0, stream>>>(Xg, WupT, counts, hmid);
    moe_gemm2<<<2048, 256, 0, stream>>>(hmid, WdownT, counts, list_tok, list_w, out);
}

// Round 17
// 345.005 us; speedup vs baseline: 1.3093x; 1.0703x over previous
//
#include <hip/hip_runtime.h>
#include <math.h>

#define T_TOK 4096
#define H_DIM 1024
#define I_DIM 2048
#define E_NUM 8
#define CAP   2048
#define BM 128
#define BN 128
#define BK 64

typedef __attribute__((ext_vector_type(8))) short bf16x8;
typedef __attribute__((ext_vector_type(4))) float f32x4;

__device__ __forceinline__ unsigned short f2bf(float f) {
    union { float f; unsigned int u; } v; v.f = f;
    unsigned int r = v.u + 0x7FFFu + ((v.u >> 16) & 1u);
    return (unsigned short)(r >> 16);
}
__device__ __forceinline__ float bf2f(unsigned short u) {
    union { unsigned int u; float f; } v; v.u = (unsigned int)u << 16;
    return v.f;
}

__device__ __forceinline__ void gl_lds16(const void* g, void* l) {
    __builtin_amdgcn_global_load_lds(
        (const __attribute__((address_space(1))) void*)g,
        (__attribute__((address_space(3))) void*)l, 16, 0, 0);
}

// ---------------- Router (atomic-free): logits -> top2 -> weights -----------
__global__ __launch_bounds__(256) void moe_router(
    const float* __restrict__ x, const float* __restrict__ gate,
    int* __restrict__ topk_idx, float* __restrict__ topk_w)
{
    const int wave = threadIdx.x >> 6;
    const int lane = threadIdx.x & 63;
    const int t = blockIdx.x * 4 + wave;

    float acc[E_NUM];
#pragma unroll
    for (int e = 0; e < E_NUM; ++e) acc[e] = 0.f;
    const float* xp = x + (size_t)t * H_DIM;
    for (int k = lane; k < H_DIM; k += 64) {
        const float xv = xp[k];
#pragma unroll
        for (int e = 0; e < E_NUM; ++e) acc[e] += xv * gate[e * H_DIM + k];
    }
#pragma unroll
    for (int e = 0; e < E_NUM; ++e) {
#pragma unroll
        for (int off = 32; off > 0; off >>= 1)
            acc[e] += __shfl_xor(acc[e], off, 64);
    }
    if (lane == 0) {
        float m = acc[0];
#pragma unroll
        for (int e = 1; e < E_NUM; ++e) m = fmaxf(m, acc[e]);
        float p[E_NUM]; float Z = 0.f;
#pragma unroll
        for (int e = 0; e < E_NUM; ++e) { p[e] = expf(acc[e] - m); Z += p[e]; }
        const float invZ = 1.f / Z;
        int i1 = 0, i2 = 0; float v1 = -1.f, v2 = -1.f;
#pragma unroll
        for (int e = 0; e < E_NUM; ++e) {
            const float pe = p[e] * invZ;
            if (pe > v1)      { v2 = v1; i2 = i1; v1 = pe; i1 = e; }
            else if (pe > v2) { v2 = pe; i2 = e; }
        }
        const float s = 1.f / (v1 + v2 + 1e-9f);
        topk_idx[t * 2 + 0] = i1; topk_idx[t * 2 + 1] = i2;
        topk_w[t * 2 + 0] = v1 * s; topk_w[t * 2 + 1] = v2 * s;
    }
}

// ---------------- Build lists: ballot-prefix scan, records positions --------
__global__ __launch_bounds__(256) void moe_build(
    const int* __restrict__ topk_idx, int* __restrict__ counts,
    int* __restrict__ list_tok, int* __restrict__ pos_arr)
{
    const int e = blockIdx.x;
    const int tid = threadIdx.x;
    const int wv = tid >> 6, lane = tid & 63;
    __shared__ int wsum[4];
    int base = 0;
    for (int c = 0; c < T_TOK; c += 256) {
        const int t = c + tid;
        const int i0 = topk_idx[t * 2 + 0];
        const int i1 = topk_idx[t * 2 + 1];
        const int match = (i0 == e) || (i1 == e);
        const int slot = (i0 == e) ? 0 : 1;
        const unsigned long long mask = __ballot(match);
        const int my = __popcll(mask & ((1ull << lane) - 1ull));
        if (lane == 0) wsum[wv] = __popcll(mask);
        __syncthreads();
        int woff = 0;
#pragma unroll
        for (int i = 0; i < 4; ++i) if (i < wv) woff += wsum[i];
        const int ctot = wsum[0] + wsum[1] + wsum[2] + wsum[3];
        if (match) {
            const int pos = base + woff + my;
            if (pos < CAP) {
                list_tok[e * CAP + pos] = t;
                pos_arr[t * 2 + slot] = e * CAP + pos;   // global row in y
            }
        }
        base += ctot;
        __syncthreads();
    }
    if (tid == 0) counts[e] = min(base, CAP);
}

// ---------------- Gather X rows -> bf16 Xg[e][CAP][H] -----------------------
__global__ __launch_bounds__(256) void moe_gather(
    const float* __restrict__ x, const int* __restrict__ counts,
    const int* __restrict__ list_tok, unsigned short* __restrict__ Xg)
{
    const int e = blockIdx.y;
    const int r = blockIdx.x;
    if (r >= min(counts[e], CAP)) return;
    const int tok = list_tok[e * CAP + r];
    const float4 v = ((const float4*)(x + (size_t)tok * H_DIM))[threadIdx.x];
    ushort4 o = make_ushort4(f2bf(v.x), f2bf(v.y), f2bf(v.z), f2bf(v.w));
    *(ushort4*)(Xg + (size_t)(e * CAP + r) * H_DIM + threadIdx.x * 4) = o;
}

// ---------------- Transpose-convert: [E][R][C] f32 -> [E][C][R] bf16 --------
__global__ __launch_bounds__(256) void transpose_bf16(
    const float* __restrict__ in, unsigned short* __restrict__ outp, int R, int C)
{
    __shared__ unsigned short t[64][72];
    const int e = blockIdx.z;
    const float* src = in + (size_t)e * R * C;
    unsigned short* dst = outp + (size_t)e * R * C;
    const int c0 = blockIdx.x * 64;
    const int r0 = blockIdx.y * 64;
    const int tx = (threadIdx.x & 15) << 2;
    const int ty = threadIdx.x >> 4;
#pragma unroll
    for (int s = 0; s < 4; ++s) {
        const int r = ty + s * 16;
        const float4 v = *(const float4*)&src[(size_t)(r0 + r) * C + c0 + tx];
        t[tx + 0][r] = f2bf(v.x);
        t[tx + 1][r] = f2bf(v.y);
        t[tx + 2][r] = f2bf(v.z);
        t[tx + 3][r] = f2bf(v.w);
    }
    __syncthreads();
    const int cc = threadIdx.x >> 3;
    const int rr = (threadIdx.x & 7) << 3;
#pragma unroll
    for (int s = 0; s < 2; ++s) {
        const int c = cc + s * 32;
        *(bf16x8*)&dst[(size_t)(c0 + c) * R + r0 + rr] = *(const bf16x8*)&t[c][rr];
    }
}

// ---- LDS swizzle (T2, rule #21): linear gl_lds dest + inverse-swizzled
// global source + swizzled read (verified R15: bank conflicts 1.3e7 -> 0).
// ---- Counted-vmcnt 2-barrier K-loop (T4): STAGE(next); vmcnt(8) drains the
// PREVIOUS batch (just-issued 8 stay in flight); barrier #1 globalizes the
// per-wave drain (buffer ready); compute; barrier #2 (ds_reads retired via
// lgkm-before-MFMA) before next iteration's overwrite. Last iter: vmcnt(0).

// ---------------- GEMM1: hmid = silu(Xg @ Wup) ------------------------------
__global__ __launch_bounds__(256) void moe_gemm1(
    const unsigned short* __restrict__ Xg, const unsigned short* __restrict__ WupT,
    const int* __restrict__ counts, unsigned short* __restrict__ hmid)
{
    __shared__ unsigned short As[2][BM][BK];
    __shared__ unsigned short Bs[2][BN][BK];
    const int s_id = blockIdx.x;
    const int l = (s_id & 7) * 256 + (s_id >> 3);  // bijective: 2048 = 8*256
    const int e = l >> 8;
    const int bx = l & 15;
    const int by = (l >> 4) & 15;
    const int cnt = min(counts[e], CAP);
    const int row0 = bx * BM;
    if (row0 >= cnt) return;
    const int n0 = by * BN;
    const int tid = threadIdx.x;
    const int lane = tid & 63;
    const int wid = tid >> 6;
    const int wm = wid >> 1, wn = wid & 1;

    const unsigned short* Ae = Xg + (size_t)e * CAP * H_DIM;
    const unsigned short* Be = WupT + (size_t)e * (size_t)I_DIM * H_DIM;

    const int sub = lane >> 3;
    const int kus = ((lane & 7) ^ sub) * 8;          // inverse-swizzled k source

#define STAGE1(buf, kt)                                                       \
    {                                                                         \
        _Pragma("unroll")                                                     \
        for (int c = 0; c < 4; ++c) {                                         \
            const int row = (c * 4 + wid) * 8 + sub;                          \
            gl_lds16(Ae + (size_t)(row0 + row) * H_DIM + (kt) + kus,          \
                     (char*)&As[buf][0][0] + (c * 4 + wid) * 1024);           \
            gl_lds16(Be + (size_t)(n0 + row) * H_DIM + (kt) + kus,            \
                     (char*)&Bs[buf][0][0] + (c * 4 + wid) * 1024);           \
        }                                                                     \
    }

    f32x4 acc[4][4];
#pragma unroll
    for (int m = 0; m < 4; ++m)
#pragma unroll
        for (int n = 0; n < 4; ++n) acc[m][n] = (f32x4){0.f, 0.f, 0.f, 0.f};

    STAGE1(0, 0);
    asm volatile("s_waitcnt vmcnt(0)" ::: "memory");
    __builtin_amdgcn_s_barrier();
    int cur = 0;
    for (int kt = 0; kt < H_DIM; kt += BK) {
        if (kt + BK < H_DIM) {
            STAGE1(cur ^ 1, kt + BK);
            asm volatile("s_waitcnt vmcnt(8)" ::: "memory");
        } else {
            asm volatile("s_waitcnt vmcnt(0)" ::: "memory");
        }
        __builtin_amdgcn_s_barrier();          // buf[cur] globally ready
        __builtin_amdgcn_sched_barrier(0);
#pragma unroll
        for (int kk = 0; kk < BK; kk += 32) {
            const int koff = ((((kk >> 3) | (lane >> 4)) ^ (lane & 7)) << 3);
            bf16x8 a[4], b[4];
#pragma unroll
            for (int m = 0; m < 4; ++m)
                a[m] = *(const bf16x8*)&As[cur][wm * 64 + m * 16 + (lane & 15)][koff];
#pragma unroll
            for (int n = 0; n < 4; ++n)
                b[n] = *(const bf16x8*)&Bs[cur][wn * 64 + n * 16 + (lane & 15)][koff];
#pragma unroll
            for (int m = 0; m < 4; ++m)
#pragma unroll
                for (int n = 0; n < 4; ++n)
                    acc[m][n] = __builtin_amdgcn_mfma_f32_16x16x32_bf16(
                        a[m], b[n], acc[m][n], 0, 0, 0);
        }
        __builtin_amdgcn_s_barrier();          // reads done before overwrite
        cur ^= 1;
    }
#undef STAGE1

    unsigned short* He = hmid + (size_t)e * CAP * I_DIM;
#pragma unroll
    for (int m = 0; m < 4; ++m) {
        const int rb = row0 + wm * 64 + m * 16 + ((lane >> 4) << 2);
#pragma unroll
        for (int n = 0; n < 4; ++n) {
            const int col = n0 + wn * 64 + n * 16 + (lane & 15);
#pragma unroll
            for (int j = 0; j < 4; ++j) {
                const float v = acc[m][n][j];
                const float s = v / (1.f + __expf(-v));
                He[(size_t)(rb + j) * I_DIM + col] = f2bf(s);
            }
        }
    }
}

// ---------------- GEMM2: y[e] = hmid[e] @ Wdown[e], plain bf16 stores -------
__global__ __launch_bounds__(256) void moe_gemm2(
    const unsigned short* __restrict__ hmid, const unsigned short* __restrict__ WdownT,
    const int* __restrict__ counts, unsigned short* __restrict__ y)
{
    __shared__ unsigned short As[2][BM][BK];
    __shared__ unsigned short Bs[2][BN][BK];
    const int s_id = blockIdx.x;
    const int l = (s_id & 7) * 128 + (s_id >> 3);  // bijective: 1024 = 8*128
    const int e = l >> 7;
    const int bx = l & 15;
    const int by = (l >> 4) & 7;
    const int cnt = min(counts[e], CAP);
    const int row0 = bx * BM;
    if (row0 >= cnt) return;
    const int n0 = by * BN;
    const int tid = threadIdx.x;
    const int lane = tid & 63;
    const int wid = tid >> 6;
    const int wm = wid >> 1, wn = wid & 1;

    const unsigned short* Ae = hmid + (size_t)e * CAP * I_DIM;
    const unsigned short* Be = WdownT + (size_t)e * (size_t)H_DIM * I_DIM;

    const int sub = lane >> 3;
    const int kus = ((lane & 7) ^ sub) * 8;

#define STAGE2(buf, kt)                                                       \
    {                                                                         \
        _Pragma("unroll")                                                     \
        for (int c = 0; c < 4; ++c) {                                         \
            const int row = (c * 4 + wid) * 8 + sub;                          \
            gl_lds16(Ae + (size_t)(row0 + row) * I_DIM + (kt) + kus,          \
                     (char*)&As[buf][0][0] + (c * 4 + wid) * 1024);           \
            gl_lds16(Be + (size_t)(n0 + row) * I_DIM + (kt) + kus,            \
                     (char*)&Bs[buf][0][0] + (c * 4 + wid) * 1024);           \
        }                                                                     \
    }

    f32x4 acc[4][4];
#pragma unroll
    for (int m = 0; m < 4; ++m)
#pragma unroll
        for (int n = 0; n < 4; ++n) acc[m][n] = (f32x4){0.f, 0.f, 0.f, 0.f};

    STAGE2(0, 0);
    asm volatile("s_waitcnt vmcnt(0)" ::: "memory");
    __builtin_amdgcn_s_barrier();
    int cur = 0;
    for (int kt = 0; kt < I_DIM; kt += BK) {
        if (kt + BK < I_DIM) {
            STAGE2(cur ^ 1, kt + BK);
            asm volatile("s_waitcnt vmcnt(8)" ::: "memory");
        } else {
            asm volatile("s_waitcnt vmcnt(0)" ::: "memory");
        }
        __builtin_amdgcn_s_barrier();
        __builtin_amdgcn_sched_barrier(0);
#pragma unroll
        for (int kk = 0; kk < BK; kk += 32) {
            const int koff = ((((kk >> 3) | (lane >> 4)) ^ (lane & 7)) << 3);
            bf16x8 a[4], b[4];
#pragma unroll
            for (int m = 0; m < 4; ++m)
                a[m] = *(const bf16x8*)&As[cur][wm * 64 + m * 16 + (lane & 15)][koff];
#pragma unroll
            for (int n = 0; n < 4; ++n)
                b[n] = *(const bf16x8*)&Bs[cur][wn * 64 + n * 16 + (lane & 15)][koff];
#pragma unroll
            for (int m = 0; m < 4; ++m)
#pragma unroll
                for (int n = 0; n < 4; ++n)
                    acc[m][n] = __builtin_amdgcn_mfma_f32_16x16x32_bf16(
                        a[m], b[n], acc[m][n], 0, 0, 0);
        }
        __builtin_amdgcn_s_barrier();
        cur ^= 1;
    }
#undef STAGE2

    unsigned short* Ye = y + (size_t)e * CAP * H_DIM;
#pragma unroll
    for (int m = 0; m < 4; ++m) {
#pragma unroll
        for (int j = 0; j < 4; ++j) {
            const int gr = row0 + wm * 64 + m * 16 + ((lane >> 4) << 2) + j;
            if (gr < cnt) {
#pragma unroll
                for (int n = 0; n < 4; ++n) {
                    const int col = n0 + wn * 64 + n * 16 + (lane & 15);
                    Ye[(size_t)gr * H_DIM + col] = f2bf(acc[m][n][j]);
                }
            }
        }
    }
}

// ---------------- Combine: out[t] = w0*y[p0] + w1*y[p1] (no atomics) --------
__global__ __launch_bounds__(256) void moe_combine(
    const unsigned short* __restrict__ y, const int* __restrict__ pos_arr,
    const float* __restrict__ topk_w, float* __restrict__ out)
{
    const int t = blockIdx.x;
    const int p0 = pos_arr[t * 2 + 0];
    const int p1 = pos_arr[t * 2 + 1];
    const float w0 = topk_w[t * 2 + 0];
    const float w1 = topk_w[t * 2 + 1];
    const int h = threadIdx.x * 4;
    const ushort4 a = *(const ushort4*)&y[(size_t)p0 * H_DIM + h];
    const ushort4 b = *(const ushort4*)&y[(size_t)p1 * H_DIM + h];
    float4 o;
    o.x = w0 * bf2f(a.x) + w1 * bf2f(b.x);
    o.y = w0 * bf2f(a.y) + w1 * bf2f(b.y);
    o.z = w0 * bf2f(a.z) + w1 * bf2f(b.z);
    o.w = w0 * bf2f(a.w) + w1 * bf2f(b.w);
    *(float4*)&out[(size_t)t * H_DIM + h] = o;
}

extern "C" void kernel_launch(void* const* d_in, const int* in_sizes, int n_in,
                              void* d_out, int out_size, void* d_ws, size_t ws_size,
                              hipStream_t stream)
{
    const float* x      = (const float*)d_in[0];   // [T, H]
    const float* gate   = (const float*)d_in[1];   // [E, H]
    const float* w_up   = (const float*)d_in[2];   // [E, H, I]
    const float* w_down = (const float*)d_in[3];   // [E, I, H]
    float* out = (float*)d_out;                    // [T, H]

    char* ws = (char*)d_ws;
    int*   counts   = (int*)(ws);                          // 1 KB
    int*   topk_idx = (int*)(ws + 1024);                   // 32 KB
    float* topk_w   = (float*)(ws + 33792);                // 32 KB
    int*   list_tok = (int*)(ws + 66560);                  // 64 KB
    int*   pos_arr  = (int*)(ws + 132096);                 // 32 KB
    unsigned short* Xg     = (unsigned short*)(ws + 197632);                  // 32 MB (aliased as y after gemm1)
    unsigned short* WupT   = (unsigned short*)(ws + 197632 + 33554432ull);    // 32 MB
    unsigned short* WdownT = (unsigned short*)(ws + 197632 + 67108864ull);    // 32 MB
    unsigned short* hmid   = (unsigned short*)(ws + 197632 + 100663296ull);   // 64 MB
    unsigned short* y      = Xg;   // Xg is dead after gemm1

    moe_router<<<T_TOK / 4, 256, 0, stream>>>(x, gate, topk_idx, topk_w);
    moe_build<<<E_NUM, 256, 0, stream>>>(topk_idx, counts, list_tok, pos_arr);
    moe_gather<<<dim3(CAP, E_NUM), 256, 0, stream>>>(x, counts, list_tok, Xg);
    transpose_bf16<<<dim3(I_DIM / 64, H_DIM / 64, E_NUM), 256, 0, stream>>>(w_up, WupT, H_DIM, I_DIM);
    transpose_bf16<<<dim3(H_DIM / 64, I_DIM / 64, E_NUM), 256, 0, stream>>>(w_down, WdownT, I_DIM, H_DIM);
    moe_gemm1<<<2048, 256, 0, stream>>>(Xg, WupT, counts, hmid);
    moe_gemm2<<<1024, 256, 0, stream>>>(hmid, WdownT, counts, y);
    moe_combine<<<T_TOK, 256, 0, stream>>>(y, pos_arr, topk_w, out);
}